// Round 12
// baseline (400.909 us; speedup 1.0000x reference)
//
#include <hip/hip_runtime.h>
#include <hip/hip_bf16.h>
#include <stdint.h>

#define NROWS   32768     // 32*32*32
#define DIMD    256
#define NATOMS  1024

typedef short  bf16x8 __attribute__((ext_vector_type(8)));
typedef float  f32x4  __attribute__((ext_vector_type(4)));

__device__ __forceinline__ unsigned short bf16rne(float f) {
    unsigned u = __float_as_uint(f);
    u = u + 0x7FFFu + ((u >> 16) & 1u);
    return (unsigned short)(u >> 16);
}
__device__ __forceinline__ float bf16f(short h) {
    return __uint_as_float(((unsigned)(unsigned short)h) << 16);
}

// ---------------------------------------------------------------------------
// B prep: planes Bs[2][8][1024][32] bf16 (m: 0=rep,1=dict; kc; atom; k-in-32)
// K-major tiling -> each MFMA atom-fragment is a contiguous 1KB global read.
// Also dict row norms (fp32).
__global__ __launch_bounds__(256) void vq_bprep(
    const float* __restrict__ rep_w, const float* __restrict__ dict_w,
    unsigned short* __restrict__ Bs, float* __restrict__ dnorm)
{
    const int tid = threadIdx.x;
    const int atom = blockIdx.x * 32 + (tid >> 3);   // 32 blocks
    const int kc = tid & 7;                          // k-chunk of 32
    float ss = 0.f;
#pragma unroll
    for (int m = 0; m < 2; ++m) {
        const float* src = (m ? dict_w : rep_w) + (size_t)atom * DIMD + kc * 32;
        unsigned short* dst = Bs + (size_t)m * 262144 + (size_t)kc * 32768 + atom * 32;
#pragma unroll
        for (int q = 0; q < 8; ++q) {
            float4 v = *(const float4*)&src[q * 4];
            float fv[4] = {v.x, v.y, v.z, v.w};
            unsigned short a0[4];
#pragma unroll
            for (int e = 0; e < 4; ++e) {
                if (m) ss = fmaf(fv[e], fv[e], ss);
                a0[e] = bf16rne(fv[e]);
            }
            *(ushort4*)&dst[q * 4] = make_ushort4(a0[0], a0[1], a0[2], a0[3]);
        }
    }
    ss += __shfl_down(ss, 4, 8);
    ss += __shfl_down(ss, 2, 8);
    ss += __shfl_down(ss, 1, 8);
    if (kc == 0) dnorm[atom] = ss;
}

// ---------------------------------------------------------------------------
// Branch-free insert of key u into sorted-ascending 8-list: clamp chain.
__device__ __forceinline__ void insk(unsigned u, unsigned (&kd)[8]) {
#pragma unroll
    for (int j = 7; j >= 1; --j)
        kd[j] = min(max(u, kd[j - 1]), kd[j]);
    kd[0] = min(u, kd[0]);
}

// in-wave merge of sorted key-lists over lane-groups (parts in lanes c+16k)
__device__ __forceinline__ void wave_merge_k(int lane, unsigned (&kd)[8], float& se) {
#pragma unroll
    for (int half = 32; half >= 16; half >>= 1) {
        const int src = (lane + half) & 63;
        unsigned ko[8];
#pragma unroll
        for (int j = 0; j < 8; ++j) ko[j] = (unsigned)__shfl((int)kd[j], src, 64);
        const float so = __shfl(se, src, 64);
        if (lane < half) {
            se += so;
#pragma unroll
            for (int t = 0; t < 8; ++t) insk(ko[t], kd);
        }
    }
}

// ---------------------------------------------------------------------------
// Main: dual GEMM (logits+dists, bf16) with swapped MFMA operands. Top-8 as
// packed keys: (sortable_dist & ~1023) | atom. Epilogue logit recovery uses
// the bf16 A-fragments already in registers (identical in all 4 waves) +
// shfl_xor reduce -- no z_e LDS slab. No global atomics here (hist kernel).
// Block = 32 rows x 4 atom-quarters, grid 1024 -> 4 blocks/CU co-resident.
__global__ __launch_bounds__(256, 3) void vq_main(
    const float* __restrict__ z_e, const unsigned short* __restrict__ Bs,
    const float* __restrict__ rep_b, const float* __restrict__ dnorm,
    float* __restrict__ rep_sparse, int* __restrict__ idx_out,
    float* __restrict__ w_out)
{
    __shared__ __align__(16) float rbS[1024];
    __shared__ __align__(16) float dnS[1024];
    __shared__ unsigned mKu[3][32][8];
    __shared__ float mS[3][32];
    __shared__ unsigned fK[32][8];
    __shared__ float fSum[32];

    const int tid = threadIdx.x;
    const int lane = tid & 63, w = tid >> 6;     // w = atom quarter
    const int c = lane & 15, lg = lane >> 4;
    const int row0 = blockIdx.x * 32;
    const int bb = row0 >> 10, hw0 = row0 & 1023;

    for (int i = tid; i < 1024; i += 256) { rbS[i] = rep_b[i]; dnS[i] = dnorm[i]; }

    const char* pL = (const char*)Bs;             // rep plane  [8][1024][32]
    const char* pD = (const char*)Bs + 524288;    // dict plane
    const int abase = w << 8;                     // 256 atoms per quarter

    // first B tile (atoms abase..abase+15): frag = 16 atoms x 32k, 1KB each
    bf16x8 bL[8], bD[8];
    {
        const int off = ((abase + c) << 6) + (lg << 4);
#pragma unroll
        for (int kc = 0; kc < 8; ++kc) {
            bL[kc] = *(const bf16x8*)(pL + ((size_t)kc << 16) + off);
            bD[kc] = *(const bf16x8*)(pD + ((size_t)kc << 16) + off);
        }
    }

    // A: rows rf*16 + c (rf=0,1), k = kc*32 + lg*8 + e, bf16 1-term.
    // NOTE: identical across the 4 waves (no w dependence) -- exploited in
    // the epilogue for distributed logit recovery.
    bf16x8 A0[8], A1[8];
    {
        const float* zb = z_e + (size_t)bb * 262144 + hw0 + c;
#pragma unroll
        for (int kc = 0; kc < 8; ++kc) {
            float f0[8], f1[8];
#pragma unroll
            for (int e = 0; e < 8; ++e) {
                const float* p = zb + (size_t)(kc * 32 + lg * 8 + e) * 1024;
                f0[e] = p[0];
                f1[e] = p[16];
            }
#pragma unroll
            for (int e = 0; e < 8; ++e) {
                A0[kc][e] = (short)bf16rne(f0[e]);
                A1[kc][e] = (short)bf16rne(f1[e]);
            }
        }
    }
    __syncthreads();   // tables staged

    // per-lane online state: frag0 = row c, frag1 = row 16+c (part lg, quarter w)
    unsigned kd0[8], kd1[8];
    float se0 = 0.f, se1 = 0.f;
#pragma unroll
    for (int j = 0; j < 8; ++j) { kd0[j] = 0xFFFFFFFFu; kd1[j] = 0xFFFFFFFFu; }

    for (int it = 0; it < 16; ++it) {
        // table prefetch for this iter's 4 atoms (hidden under MFMA block)
        const int tb = abase + (it << 4) + (lg << 2);
        const f32x4 rbv = *(const f32x4*)&rbS[tb];
        const f32x4 dnv = *(const f32x4*)&dnS[tb];

        f32x4 aL0 = {0.f,0.f,0.f,0.f}, aD0 = {0.f,0.f,0.f,0.f};
        f32x4 aL1 = {0.f,0.f,0.f,0.f}, aD1 = {0.f,0.f,0.f,0.f};
        // D[atom][flatrow]: A-operand = atom frag, B-operand = flat-row frag
#pragma unroll
        for (int kc = 0; kc < 8; ++kc) {
            aL0 = __builtin_amdgcn_mfma_f32_16x16x32_bf16(bL[kc], A0[kc], aL0, 0, 0, 0);
            aD0 = __builtin_amdgcn_mfma_f32_16x16x32_bf16(bD[kc], A0[kc], aD0, 0, 0, 0);
            aL1 = __builtin_amdgcn_mfma_f32_16x16x32_bf16(bL[kc], A1[kc], aL1, 0, 0, 0);
            aD1 = __builtin_amdgcn_mfma_f32_16x16x32_bf16(bD[kc], A1[kc], aD1, 0, 0, 0);
        }

        // prefetch next B tile (regs free after last MFMA read)
        if (it < 15) {
            const int off = ((abase + (it + 1) * 16 + c) << 6) + (lg << 4);
#pragma unroll
            for (int kc = 0; kc < 8; ++kc) {
                bL[kc] = *(const bf16x8*)(pL + ((size_t)kc << 16) + off);
                bD[kc] = *(const bf16x8*)(pD + ((size_t)kc << 16) + off);
            }
        }

        // scan: atoms tb+q for rows c (frag0) and 16+c (frag1); branch-free
#pragma unroll
        for (int q = 0; q < 4; ++q) {
            const unsigned atom = (unsigned)(tb + q);
            se0 += __expf(aL0[q] + rbv[q]);
            se1 += __expf(aL1[q] + rbv[q]);
            unsigned u0 = __float_as_uint(dnv[q] - 2.0f * aD0[q]);
            u0 ^= ((unsigned)((int)u0 >> 31) | 0x80000000u);
            unsigned u1 = __float_as_uint(dnv[q] - 2.0f * aD1[q]);
            u1 ^= ((unsigned)((int)u1 >> 31) | 0x80000000u);
            insk((u0 & ~1023u) | atom, kd0);
            insk((u1 & ~1023u) | atom, kd1);
        }
    }

    // ---- in-wave merges (parts lg -> lanes 0..15), both frags
    wave_merge_k(lane, kd0, se0);
    wave_merge_k(lane, kd1, se1);

    // quarters 1..3 publish to LDS
    if (w >= 1 && lane < 16) {
#pragma unroll
        for (int j = 0; j < 8; ++j) {
            mKu[w - 1][c][j] = kd0[j];
            mKu[w - 1][16 + c][j] = kd1[j];
        }
        mS[w - 1][c] = se0;
        mS[w - 1][16 + c] = se1;
    }
    __syncthreads();

    // zero-fill this block's 32 rows of rep_sparse (replaces memset kernel)
    {
        float4 z4 = {0.f, 0.f, 0.f, 0.f};
        float4* rp4 = (float4*)rep_sparse + (size_t)row0 * (NATOMS / 4) + tid;
        for (int r = 0; r < 32; ++r)
            rp4[(size_t)r * (NATOMS / 4)] = z4;
    }

    // quarter-0 wave: merge other quarters, publish final keys + sums
    if (w == 0 && lane < 16) {
        for (int p = 0; p < 3; ++p)
#pragma unroll
            for (int t = 0; t < 8; ++t) {
                insk(mKu[p][c][t], kd0);
                insk(mKu[p][16 + c][t], kd1);
            }
        se0 += mS[0][c] + mS[1][c] + mS[2][c];
        se1 += mS[0][16 + c] + mS[1][16 + c] + mS[2][16 + c];
#pragma unroll
        for (int j = 0; j < 8; ++j) { fK[c][j] = kd0[j]; fK[16 + c][j] = kd1[j]; }
        fSum[c] = se0;
        fSum[16 + c] = se1;
    }
    __syncthreads();   // fK/fSum visible; zero stores drained

    // ---- distributed logit recovery: wave w handles slots w and w+4.
    // Lane (c,lg) computes the k-slice partial dot from its A-regs, then
    // shfl_xor reduce over the lg group; lg==0 lanes finalize + scatter.
#pragma unroll
    for (int js = 0; js < 2; ++js) {
        const int j = w + js * 4;
        const int idx0 = (int)(fK[c][j] & 1023u);
        const int idx1 = (int)(fK[16 + c][j] & 1023u);
        float acc0 = 0.f, acc1 = 0.f;
#pragma unroll
        for (int kc = 0; kc < 8; ++kc) {
            bf16x8 r0 = *(const bf16x8*)(pL + ((size_t)kc << 16) + idx0 * 64 + lg * 16);
            bf16x8 r1 = *(const bf16x8*)(pL + ((size_t)kc << 16) + idx1 * 64 + lg * 16);
#pragma unroll
            for (int e = 0; e < 8; ++e) {
                acc0 = fmaf(bf16f(A0[kc][e]), bf16f(r0[e]), acc0);
                acc1 = fmaf(bf16f(A1[kc][e]), bf16f(r1[e]), acc1);
            }
        }
        acc0 += __shfl_xor(acc0, 16, 64);
        acc0 += __shfl_xor(acc0, 32, 64);
        acc1 += __shfl_xor(acc1, 16, 64);
        acc1 += __shfl_xor(acc1, 32, 64);
        if (lg == 0) {
            const float wv0 = __expf(acc0 + rbS[idx0]) * 0.125f / fSum[c];
            int row = row0 + c;
            idx_out[row * 8 + j] = idx0;
            w_out[row * 8 + j] = wv0;
            rep_sparse[(size_t)row * NATOMS + idx0] = wv0;
            const float wv1 = __expf(acc1 + rbS[idx1]) * 0.125f / fSum[16 + c];
            row = row0 + 16 + c;
            idx_out[row * 8 + j] = idx1;
            w_out[row * 8 + j] = wv1;
            rep_sparse[(size_t)row * NATOMS + idx1] = wv1;
        }
    }
}

// ---------------------------------------------------------------------------
// Histogram of selected indices (for perplexity), LDS-aggregated.
__global__ __launch_bounds__(256) void vq_hist(
    const int* __restrict__ idx_in, int* __restrict__ counts)
{
    __shared__ int h[1024];
    const int tid = threadIdx.x;
    for (int i = tid; i < 1024; i += 256) h[i] = 0;
    __syncthreads();
    const int4* p = (const int4*)(idx_in + blockIdx.x * 16384) + tid;
    for (int t = 0; t < 16; ++t) {
        int4 v = p[t * 256];
        atomicAdd(&h[v.x], 1); atomicAdd(&h[v.y], 1);
        atomicAdd(&h[v.z], 1); atomicAdd(&h[v.w], 1);
    }
    __syncthreads();
    for (int i = tid; i < 1024; i += 256)
        if (h[i]) atomicAdd(&counts[i], h[i]);
}

// ---------------------------------------------------------------------------
// Reconstruct z_dl, write z_st (NCHW), accumulate squared-error partials.
__global__ __launch_bounds__(256, 2) void vq_recon(
    const float* __restrict__ z_e, const float* __restrict__ dict_w,
    const int* __restrict__ idx_in, const float* __restrict__ w_in,
    float* __restrict__ z_st, float* __restrict__ partials)
{
    __shared__ float zdl[32][257];
    __shared__ float red[256];
    const int tid = threadIdx.x;
    const int row0 = blockIdx.x * 32;

    for (int r = 0; r < 32; ++r) {
        const int row = row0 + r;
        float acc = 0.f;
#pragma unroll
        for (int j = 0; j < 8; ++j) {
            const int ix = idx_in[row * 8 + j];
            const float wv = w_in[row * 8 + j];
            acc = fmaf(wv, dict_w[(size_t)ix * DIMD + tid], acc);
        }
        zdl[r][tid] = acc;
    }
    __syncthreads();

    const int bb = row0 >> 10, hw0 = row0 & 1023;
    const float* zb = z_e + (size_t)bb * (DIMD * 1024) + hw0;
    float* ob = z_st + (size_t)bb * (DIMD * 1024) + hw0;
    const int m = tid & 31, dg = tid >> 5;
    float sacc = 0.f;
    for (int itr = 0; itr < 32; ++itr) {
        const int d = itr * 8 + dg;
        const float ze = zb[(size_t)d * 1024 + m];
        const float zd = zdl[m][d];
        const float diff = zd - ze;
        ob[(size_t)d * 1024 + m] = ze + diff;   // reference rounding path
        sacc = fmaf(diff, diff, sacc);
    }
    red[tid] = sacc;
    __syncthreads();
    for (int s = 128; s > 0; s >>= 1) {
        if (tid < s) red[tid] += red[tid + s];
        __syncthreads();
    }
    if (tid == 0) partials[blockIdx.x] = red[0];
}

// ---------------------------------------------------------------------------
// Finalize: loss and perplexity (deterministic fixed-order reductions)
__global__ void vq_final(const float* __restrict__ partials,
                         const int* __restrict__ counts,
                         float* __restrict__ out_loss, float* __restrict__ out_perp)
{
    __shared__ double dred[256];
    __shared__ float fred[256];
    const int tid = threadIdx.x;
    double s = 0.0;
    for (int i = tid; i < 1024; i += 256) s += (double)partials[i];
    dred[tid] = s;
    __syncthreads();
    for (int st = 128; st > 0; st >>= 1) {
        if (tid < st) dred[tid] += dred[tid + st];
        __syncthreads();
    }
    float ps = 0.f;
    for (int i = tid; i < NATOMS; i += 256) {
        const float p = (float)counts[i] * (1.0f / 262144.0f);
        ps += p * logf(p + 1e-10f);
    }
    fred[tid] = ps;
    __syncthreads();
    for (int st = 128; st > 0; st >>= 1) {
        if (tid < st) fred[tid] += fred[tid + st];
        __syncthreads();
    }
    if (tid == 0) {
        *out_loss = 0.25f * (float)(dred[0] / 8388608.0);
        *out_perp = expf(-fred[0]);
    }
}

// ---------------------------------------------------------------------------
extern "C" void kernel_launch(void* const* d_in, const int* in_sizes, int n_in,
                              void* d_out, int out_size, void* d_ws, size_t ws_size,
                              hipStream_t stream) {
    const float* z_e    = (const float*)d_in[0];
    const float* dict_w = (const float*)d_in[1];
    const float* rep_w  = (const float*)d_in[2];
    const float* rep_b  = (const float*)d_in[3];

    float* out = (float*)d_out;
    float* out_loss   = out;                      // [0]
    float* z_st       = out + 1;                  // [1 .. 8388608]
    float* out_perp   = out + 1 + 8388608;        // [8388609]
    float* rep_sparse = out + 2 + 8388608;        // [8388610 ..] 32768x1024

    // Bs scratch (1 MB, 2 planes) parked INSIDE the z_st output region
    // (offset 16 MB). vq_recon rewrites all of z_st after vq_main finishes,
    // so no live data is clobbered and nothing leaks across calls.
    unsigned short* Bs = (unsigned short*)((((uintptr_t)(z_st + 4194304)) + 255) & ~(uintptr_t)255);

    char* ws = (char*)d_ws;
    int*   idx_out  = (int*)ws;                             // 1 MB
    float* w_out    = (float*)(ws + (1 << 20));             // 1 MB
    int*   counts   = (int*)(ws + (2 << 20));               // 4 KB
    float* dnorm    = (float*)(ws + (2 << 20) + 4096);      // 4 KB
    float* partials = (float*)(ws + (2 << 20) + 8192);      // 4 KB

    (void)hipMemsetAsync(counts, 0, NATOMS * sizeof(int), stream);

    vq_bprep<<<32, 256, 0, stream>>>(rep_w, dict_w, Bs, dnorm);
    vq_main<<<NROWS / 32, 256, 0, stream>>>(z_e, Bs, rep_b, dnorm,
                                            rep_sparse, idx_out, w_out);
    vq_hist<<<16, 256, 0, stream>>>(idx_out, counts);
    vq_recon<<<NROWS / 32, 256, 0, stream>>>(z_e, dict_w, idx_out, w_out, z_st, partials);
    vq_final<<<1, 256, 0, stream>>>(partials, counts, out_loss, out_perp);
}

// Round 13
// 166.939 us; speedup vs baseline: 2.4015x; 2.4015x over previous
//
#include <hip/hip_runtime.h>
#include <hip/hip_bf16.h>
#include <stdint.h>

#define NROWS   32768     // 32*32*32
#define DIMD    256
#define NATOMS  1024

typedef short  bf16x8 __attribute__((ext_vector_type(8)));
typedef float  f32x4  __attribute__((ext_vector_type(4)));

__device__ __forceinline__ unsigned short bf16rne(float f) {
    unsigned u = __float_as_uint(f);
    u = u + 0x7FFFu + ((u >> 16) & 1u);
    return (unsigned short)(u >> 16);
}
__device__ __forceinline__ float bf16f(short h) {
    return __uint_as_float(((unsigned)(unsigned short)h) << 16);
}

// ---------------------------------------------------------------------------
// B prep: planes Bs[2][8][1024][32] bf16 (m: 0=rep,1=dict; kc; atom; k-in-32)
// K-major tiling -> each MFMA atom-fragment is a contiguous 1KB global read.
// Also dict row norms (fp32).
__global__ __launch_bounds__(256) void vq_bprep(
    const float* __restrict__ rep_w, const float* __restrict__ dict_w,
    unsigned short* __restrict__ Bs, float* __restrict__ dnorm)
{
    const int tid = threadIdx.x;
    const int atom = blockIdx.x * 32 + (tid >> 3);   // 32 blocks
    const int kc = tid & 7;                          // k-chunk of 32
    float ss = 0.f;
#pragma unroll
    for (int m = 0; m < 2; ++m) {
        const float* src = (m ? dict_w : rep_w) + (size_t)atom * DIMD + kc * 32;
        unsigned short* dst = Bs + (size_t)m * 262144 + (size_t)kc * 32768 + atom * 32;
#pragma unroll
        for (int q = 0; q < 8; ++q) {
            float4 v = *(const float4*)&src[q * 4];
            float fv[4] = {v.x, v.y, v.z, v.w};
            unsigned short a0[4];
#pragma unroll
            for (int e = 0; e < 4; ++e) {
                if (m) ss = fmaf(fv[e], fv[e], ss);
                a0[e] = bf16rne(fv[e]);
            }
            *(ushort4*)&dst[q * 4] = make_ushort4(a0[0], a0[1], a0[2], a0[3]);
        }
    }
    ss += __shfl_down(ss, 4, 8);
    ss += __shfl_down(ss, 2, 8);
    ss += __shfl_down(ss, 1, 8);
    if (kc == 0) dnorm[atom] = ss;
}

// ---------------------------------------------------------------------------
// Branch-free insert of key u into sorted-ascending 8-list: clamp chain.
__device__ __forceinline__ void insk(unsigned u, unsigned (&kd)[8]) {
#pragma unroll
    for (int j = 7; j >= 1; --j)
        kd[j] = min(max(u, kd[j - 1]), kd[j]);
    kd[0] = min(u, kd[0]);
}

// in-wave merge of sorted key-lists over lane-groups (parts in lanes c+16k)
__device__ __forceinline__ void wave_merge_k(int lane, unsigned (&kd)[8], float& se) {
#pragma unroll
    for (int half = 32; half >= 16; half >>= 1) {
        const int src = (lane + half) & 63;
        unsigned ko[8];
#pragma unroll
        for (int j = 0; j < 8; ++j) ko[j] = (unsigned)__shfl((int)kd[j], src, 64);
        const float so = __shfl(se, src, 64);
        if (lane < half) {
            se += so;
#pragma unroll
            for (int t = 0; t < 8; ++t) insk(ko[t], kd);
        }
    }
}

// ---------------------------------------------------------------------------
// Main: dual GEMM (logits+dists, bf16) with swapped MFMA operands. Top-8 as
// packed keys: (sortable_dist & ~1023) | atom (22-bit dist, 10-bit idx; ties
// -> lower idx), branch-free clamp-chain insert. Epilogue recomputes the 8
// winning logits from a bf16 z_e slab in LDS (A-regs die at loop end -- do
// NOT extend their liveness; R12 spill lesson). Block = 32 rows x 4 atom-
// quarters, grid 1024; LDS ~30 KB -> 4 blocks/CU.
__global__ __launch_bounds__(256, 3) void vq_main(
    const float* __restrict__ z_e, const unsigned short* __restrict__ Bs,
    const float* __restrict__ rep_b, const float* __restrict__ dnorm,
    float* __restrict__ rep_sparse, int* __restrict__ idx_out,
    float* __restrict__ w_out)
{
    __shared__ __align__(16) float rbS[1024];
    __shared__ __align__(16) float dnS[1024];
    __shared__ __align__(16) unsigned short zSu[32][264];   // bf16 z_e slab
    __shared__ unsigned mKu[3][32][8];
    __shared__ float mS[3][32];
    __shared__ unsigned fK[32][8];
    __shared__ float fSum[32];

    const int tid = threadIdx.x;
    const int lane = tid & 63, w = tid >> 6;     // w = atom quarter
    const int c = lane & 15, lg = lane >> 4;
    const int row0 = blockIdx.x * 32;
    const int bb = row0 >> 10, hw0 = row0 & 1023;

    for (int i = tid; i < 1024; i += 256) { rbS[i] = rep_b[i]; dnS[i] = dnorm[i]; }

    const char* pL = (const char*)Bs;             // rep plane  [8][1024][32]
    const char* pD = (const char*)Bs + 524288;    // dict plane
    const int abase = w << 8;                     // 256 atoms per quarter

    // first B tile (atoms abase..abase+15): frag = 16 atoms x 32k, 1KB each
    bf16x8 bL[8], bD[8];
    {
        const int off = ((abase + c) << 6) + (lg << 4);
#pragma unroll
        for (int kc = 0; kc < 8; ++kc) {
            bL[kc] = *(const bf16x8*)(pL + ((size_t)kc << 16) + off);
            bD[kc] = *(const bf16x8*)(pD + ((size_t)kc << 16) + off);
        }
    }

    // A: rows rf*16 + c (rf=0,1), k = kc*32 + lg*8 + e, bf16 1-term.
    // The bf16 values also go to the zSu slab for the epilogue (waves 0..3
    // write identical data; harmless and saves a branch).
    bf16x8 A0[8], A1[8];
    {
        const float* zb = z_e + (size_t)bb * 262144 + hw0 + c;
#pragma unroll
        for (int kc = 0; kc < 8; ++kc) {
            float f0[8], f1[8];
#pragma unroll
            for (int e = 0; e < 8; ++e) {
                const float* p = zb + (size_t)(kc * 32 + lg * 8 + e) * 1024;
                f0[e] = p[0];
                f1[e] = p[16];
            }
#pragma unroll
            for (int e = 0; e < 8; ++e) {
                const int k = kc * 32 + lg * 8 + e;
                const unsigned short b0 = bf16rne(f0[e]);
                const unsigned short b1 = bf16rne(f1[e]);
                zSu[c][k] = b0;
                zSu[16 + c][k] = b1;
                A0[kc][e] = (short)b0;
                A1[kc][e] = (short)b1;
            }
        }
    }
    __syncthreads();   // tables + slab staged

    // per-lane online state: frag0 = row c, frag1 = row 16+c (part lg, quarter w)
    unsigned kd0[8], kd1[8];
    float se0 = 0.f, se1 = 0.f;
#pragma unroll
    for (int j = 0; j < 8; ++j) { kd0[j] = 0xFFFFFFFFu; kd1[j] = 0xFFFFFFFFu; }

    for (int it = 0; it < 16; ++it) {
        // table prefetch for this iter's 4 atoms (hidden under MFMA block)
        const int tb = abase + (it << 4) + (lg << 2);
        const f32x4 rbv = *(const f32x4*)&rbS[tb];
        const f32x4 dnv = *(const f32x4*)&dnS[tb];

        f32x4 aL0 = {0.f,0.f,0.f,0.f}, aD0 = {0.f,0.f,0.f,0.f};
        f32x4 aL1 = {0.f,0.f,0.f,0.f}, aD1 = {0.f,0.f,0.f,0.f};
        // D[atom][flatrow]: A-operand = atom frag, B-operand = flat-row frag
#pragma unroll
        for (int kc = 0; kc < 8; ++kc) {
            aL0 = __builtin_amdgcn_mfma_f32_16x16x32_bf16(bL[kc], A0[kc], aL0, 0, 0, 0);
            aD0 = __builtin_amdgcn_mfma_f32_16x16x32_bf16(bD[kc], A0[kc], aD0, 0, 0, 0);
            aL1 = __builtin_amdgcn_mfma_f32_16x16x32_bf16(bL[kc], A1[kc], aL1, 0, 0, 0);
            aD1 = __builtin_amdgcn_mfma_f32_16x16x32_bf16(bD[kc], A1[kc], aD1, 0, 0, 0);
        }

        // prefetch next B tile (regs free after last MFMA read)
        if (it < 15) {
            const int off = ((abase + (it + 1) * 16 + c) << 6) + (lg << 4);
#pragma unroll
            for (int kc = 0; kc < 8; ++kc) {
                bL[kc] = *(const bf16x8*)(pL + ((size_t)kc << 16) + off);
                bD[kc] = *(const bf16x8*)(pD + ((size_t)kc << 16) + off);
            }
        }

        // scan: atoms tb+q for rows c (frag0) and 16+c (frag1); branch-free
#pragma unroll
        for (int q = 0; q < 4; ++q) {
            const unsigned atom = (unsigned)(tb + q);
            se0 += __expf(aL0[q] + rbv[q]);
            se1 += __expf(aL1[q] + rbv[q]);
            unsigned u0 = __float_as_uint(dnv[q] - 2.0f * aD0[q]);
            u0 ^= ((unsigned)((int)u0 >> 31) | 0x80000000u);
            unsigned u1 = __float_as_uint(dnv[q] - 2.0f * aD1[q]);
            u1 ^= ((unsigned)((int)u1 >> 31) | 0x80000000u);
            insk((u0 & ~1023u) | atom, kd0);
            insk((u1 & ~1023u) | atom, kd1);
        }
    }

    // ---- in-wave merges (parts lg -> lanes 0..15), both frags
    wave_merge_k(lane, kd0, se0);
    wave_merge_k(lane, kd1, se1);
    // lanes 0..15: frag0 = row c, frag1 = row 16+c (this wave's atom quarter)

    // quarters 1..3 publish to LDS
    if (w >= 1 && lane < 16) {
#pragma unroll
        for (int j = 0; j < 8; ++j) {
            mKu[w - 1][c][j] = kd0[j];
            mKu[w - 1][16 + c][j] = kd1[j];
        }
        mS[w - 1][c] = se0;
        mS[w - 1][16 + c] = se1;
    }
    __syncthreads();

    // zero-fill this block's 32 rows of rep_sparse (replaces memset kernel)
    {
        float4 z4 = {0.f, 0.f, 0.f, 0.f};
        float4* rp4 = (float4*)rep_sparse + (size_t)row0 * (NATOMS / 4) + tid;
        for (int r = 0; r < 32; ++r)
            rp4[(size_t)r * (NATOMS / 4)] = z4;
    }

    // quarter-0 wave: merge other quarters, publish final keys + sums
    if (w == 0 && lane < 16) {
        for (int p = 0; p < 3; ++p)
#pragma unroll
            for (int t = 0; t < 8; ++t) {
                insk(mKu[p][c][t], kd0);
                insk(mKu[p][16 + c][t], kd1);
            }
        se0 += mS[0][c] + mS[1][c] + mS[2][c];
        se1 += mS[0][16 + c] + mS[1][16 + c] + mS[2][16 + c];
#pragma unroll
        for (int j = 0; j < 8; ++j) { fK[c][j] = kd0[j]; fK[16 + c][j] = kd1[j]; }
        fSum[c] = se0;
        fSum[16 + c] = se1;
    }
    __syncthreads();   // fK/fSum visible; zero stores drained

    // ---- logit recovery + scatter: thread = (slot j, row rr); z_e from the
    // bf16 LDS slab (vector reads), rep row from the L2-hot Bs plane.
    {
        const int j = tid >> 5, rr = tid & 31;
        const unsigned key = fK[rr][j];
        const int idx = (int)(key & 1023u);
        float acc = 0.f;
        for (int kc = 0; kc < 8; ++kc) {
            bf16x8 rv[4], zv[4];
#pragma unroll
            for (int m = 0; m < 4; ++m) {
                rv[m] = *(const bf16x8*)(pL + ((size_t)kc << 16) + idx * 64 + m * 16);
                zv[m] = *(const bf16x8*)&zSu[rr][kc * 32 + m * 8];
            }
#pragma unroll
            for (int m = 0; m < 4; ++m)
#pragma unroll
                for (int e = 0; e < 8; ++e)
                    acc = fmaf(bf16f(zv[m][e]), bf16f(rv[m][e]), acc);
        }
        const float l = acc + rbS[idx];
        const float wv = __expf(l) * 0.125f / fSum[rr];
        const int row = row0 + rr;
        idx_out[row * 8 + j] = idx;
        w_out[row * 8 + j] = wv;
        rep_sparse[(size_t)row * NATOMS + idx] = wv;
    }
}

// ---------------------------------------------------------------------------
// Histogram of selected indices (for perplexity), LDS-aggregated.
__global__ __launch_bounds__(256) void vq_hist(
    const int* __restrict__ idx_in, int* __restrict__ counts)
{
    __shared__ int h[1024];
    const int tid = threadIdx.x;
    for (int i = tid; i < 1024; i += 256) h[i] = 0;
    __syncthreads();
    const int4* p = (const int4*)(idx_in + blockIdx.x * 16384) + tid;
    for (int t = 0; t < 16; ++t) {
        int4 v = p[t * 256];
        atomicAdd(&h[v.x], 1); atomicAdd(&h[v.y], 1);
        atomicAdd(&h[v.z], 1); atomicAdd(&h[v.w], 1);
    }
    __syncthreads();
    for (int i = tid; i < 1024; i += 256)
        if (h[i]) atomicAdd(&counts[i], h[i]);
}

// ---------------------------------------------------------------------------
// Reconstruct z_dl, write z_st (NCHW), accumulate squared-error partials.
__global__ __launch_bounds__(256, 2) void vq_recon(
    const float* __restrict__ z_e, const float* __restrict__ dict_w,
    const int* __restrict__ idx_in, const float* __restrict__ w_in,
    float* __restrict__ z_st, float* __restrict__ partials)
{
    __shared__ float zdl[32][257];
    __shared__ float red[256];
    const int tid = threadIdx.x;
    const int row0 = blockIdx.x * 32;

    for (int r = 0; r < 32; ++r) {
        const int row = row0 + r;
        float acc = 0.f;
#pragma unroll
        for (int j = 0; j < 8; ++j) {
            const int ix = idx_in[row * 8 + j];
            const float wv = w_in[row * 8 + j];
            acc = fmaf(wv, dict_w[(size_t)ix * DIMD + tid], acc);
        }
        zdl[r][tid] = acc;
    }
    __syncthreads();

    const int bb = row0 >> 10, hw0 = row0 & 1023;
    const float* zb = z_e + (size_t)bb * (DIMD * 1024) + hw0;
    float* ob = z_st + (size_t)bb * (DIMD * 1024) + hw0;
    const int m = tid & 31, dg = tid >> 5;
    float sacc = 0.f;
    for (int itr = 0; itr < 32; ++itr) {
        const int d = itr * 8 + dg;
        const float ze = zb[(size_t)d * 1024 + m];
        const float zd = zdl[m][d];
        const float diff = zd - ze;
        ob[(size_t)d * 1024 + m] = ze + diff;   // reference rounding path
        sacc = fmaf(diff, diff, sacc);
    }
    red[tid] = sacc;
    __syncthreads();
    for (int s = 128; s > 0; s >>= 1) {
        if (tid < s) red[tid] += red[tid + s];
        __syncthreads();
    }
    if (tid == 0) partials[blockIdx.x] = red[0];
}

// ---------------------------------------------------------------------------
// Finalize: loss and perplexity (deterministic fixed-order reductions)
__global__ void vq_final(const float* __restrict__ partials,
                         const int* __restrict__ counts,
                         float* __restrict__ out_loss, float* __restrict__ out_perp)
{
    __shared__ double dred[256];
    __shared__ float fred[256];
    const int tid = threadIdx.x;
    double s = 0.0;
    for (int i = tid; i < 1024; i += 256) s += (double)partials[i];
    dred[tid] = s;
    __syncthreads();
    for (int st = 128; st > 0; st >>= 1) {
        if (tid < st) dred[tid] += dred[tid + st];
        __syncthreads();
    }
    float ps = 0.f;
    for (int i = tid; i < NATOMS; i += 256) {
        const float p = (float)counts[i] * (1.0f / 262144.0f);
        ps += p * logf(p + 1e-10f);
    }
    fred[tid] = ps;
    __syncthreads();
    for (int st = 128; st > 0; st >>= 1) {
        if (tid < st) fred[tid] += fred[tid + st];
        __syncthreads();
    }
    if (tid == 0) {
        *out_loss = 0.25f * (float)(dred[0] / 8388608.0);
        *out_perp = expf(-fred[0]);
    }
}

// ---------------------------------------------------------------------------
extern "C" void kernel_launch(void* const* d_in, const int* in_sizes, int n_in,
                              void* d_out, int out_size, void* d_ws, size_t ws_size,
                              hipStream_t stream) {
    const float* z_e    = (const float*)d_in[0];
    const float* dict_w = (const float*)d_in[1];
    const float* rep_w  = (const float*)d_in[2];
    const float* rep_b  = (const float*)d_in[3];

    float* out = (float*)d_out;
    float* out_loss   = out;                      // [0]
    float* z_st       = out + 1;                  // [1 .. 8388608]
    float* out_perp   = out + 1 + 8388608;        // [8388609]
    float* rep_sparse = out + 2 + 8388608;        // [8388610 ..] 32768x1024

    // Bs scratch (1 MB, 2 planes) parked INSIDE the z_st output region
    // (offset 16 MB). vq_recon rewrites all of z_st after vq_main finishes,
    // so no live data is clobbered and nothing leaks across calls.
    unsigned short* Bs = (unsigned short*)((((uintptr_t)(z_st + 4194304)) + 255) & ~(uintptr_t)255);

    char* ws = (char*)d_ws;
    int*   idx_out  = (int*)ws;                             // 1 MB
    float* w_out    = (float*)(ws + (1 << 20));             // 1 MB
    int*   counts   = (int*)(ws + (2 << 20));               // 4 KB
    float* dnorm    = (float*)(ws + (2 << 20) + 4096);      // 4 KB
    float* partials = (float*)(ws + (2 << 20) + 8192);      // 4 KB

    (void)hipMemsetAsync(counts, 0, NATOMS * sizeof(int), stream);

    vq_bprep<<<32, 256, 0, stream>>>(rep_w, dict_w, Bs, dnorm);
    vq_main<<<NROWS / 32, 256, 0, stream>>>(z_e, Bs, rep_b, dnorm,
                                            rep_sparse, idx_out, w_out);
    vq_hist<<<16, 256, 0, stream>>>(idx_out, counts);
    vq_recon<<<NROWS / 32, 256, 0, stream>>>(z_e, dict_w, idx_out, w_out, z_st, partials);
    vq_final<<<1, 256, 0, stream>>>(partials, counts, out_loss, out_perp);
}